// Round 4
// baseline (353.545 us; speedup 1.0000x reference)
//
#include <hip/hip_runtime.h>
#include <hip/hip_bf16.h>
#include <cstdint>

#define SDIM 8192
#define DIN  4096
#define DOUT 4096
#define KAUG 4224   // 4096 + 8*16 LoRA extension
#define NADP 8
#define RLORA 16
#define NT 66       // K-tiles of 64

typedef __attribute__((ext_vector_type(8))) short short8;
typedef __attribute__((ext_vector_type(4))) float f32x4;
typedef __attribute__((ext_vector_type(16))) float f32x16;

// ---------- conversion: f32 [rows][4096] -> bf16 [rows][KAUG] (first 4096 cols) ----------
__global__ void cvt_f32_to_bf16_aug(const float* __restrict__ src,
                                    __hip_bfloat16* __restrict__ dst,
                                    long total_elems) {
    long tid = (long)blockIdx.x * blockDim.x + threadIdx.x;
    long e = tid * 8;
    if (e >= total_elems) return;
    int s = (int)(e >> 12);
    int k = (int)(e & 4095);
    const float4* p = (const float4*)(src + e);
    float4 v0 = p[0], v1 = p[1];
    union { __hip_bfloat16 h[8]; short8 v; } u;
    u.h[0] = __float2bfloat16(v0.x); u.h[1] = __float2bfloat16(v0.y);
    u.h[2] = __float2bfloat16(v0.z); u.h[3] = __float2bfloat16(v0.w);
    u.h[4] = __float2bfloat16(v1.x); u.h[5] = __float2bfloat16(v1.y);
    u.h[6] = __float2bfloat16(v1.z); u.h[7] = __float2bfloat16(v1.w);
    *(short8*)(dst + (size_t)s * KAUG + k) = u.v;
}

// ---------- B tail into waug + A_all f32->bf16 into abf ----------
__global__ void prep_small(const float* __restrict__ B0, const float* __restrict__ A,
                           __hip_bfloat16* __restrict__ waug, __hip_bfloat16* __restrict__ abf) {
    int t = blockIdx.x * 256 + threadIdx.x;
    if (blockIdx.x < 2048) {           // btail: DOUT*128 elems
        int n = t >> 7, c = t & 127;
        int l = c >> 4, r = c & 15;
        waug[(size_t)n * KAUG + 4096 + c] =
            __float2bfloat16(B0[((size_t)l * DOUT + n) * RLORA + r]);
    } else {                           // A cvt: 128*4096 elems, 8/thread
        long e = (long)(t - 2048 * 256) * 8;
        const float4* p = (const float4*)(A + e);
        float4 v0 = p[0], v1 = p[1];
        union { __hip_bfloat16 h[8]; short8 v; } u;
        u.h[0] = __float2bfloat16(v0.x); u.h[1] = __float2bfloat16(v0.y);
        u.h[2] = __float2bfloat16(v0.z); u.h[3] = __float2bfloat16(v0.w);
        u.h[4] = __float2bfloat16(v1.x); u.h[5] = __float2bfloat16(v1.y);
        u.h[6] = __float2bfloat16(v1.z); u.h[7] = __float2bfloat16(v1.w);
        *(short8*)(abf + e) = u.v;
    }
}

// ---------- XA_all split-K mini-GEMM: part[kc][8192][128] = Xa[:, kc*1024:+1024] @ Ab^T ----------
__global__ __launch_bounds__(256) void xa_gemm(const __hip_bfloat16* __restrict__ Xa,
                                               const __hip_bfloat16* __restrict__ Ab,
                                               float* __restrict__ part) {
    __shared__ __attribute__((aligned(16))) char sm[32768];
    char* Xs = sm;              // [128][64] bf16
    char* As = sm + 16384;      // [128][64] bf16
    const int tid = threadIdx.x, lane = tid & 63, wave = tid >> 6;
    const int mt = blockIdx.x >> 2, kc = blockIdx.x & 3;
    const int row0 = mt * 128, k0 = kc * 1024;
    const int sr = tid >> 3;                 // 0..31
    const int cp = (tid & 7) ^ (sr & 7);
    const __hip_bfloat16* gX = Xa + (size_t)(row0 + sr) * KAUG + k0 + cp * 8;
    const __hip_bfloat16* gA = Ab + (size_t)sr * DIN + k0 + cp * 8;
    const int lr = lane & 15, lk = lane >> 4;
    f32x4 acc[2][8] = {};
    for (int kt = 0; kt < 16; ++kt) {
        #pragma unroll
        for (int i = 0; i < 4; ++i) {
            __builtin_amdgcn_global_load_lds((const uint32_t*)(gX + (size_t)(32 * i) * KAUG + kt * 64),
                                             (uint32_t*)(Xs + i * 4096 + tid * 16), 16, 0, 0);
            __builtin_amdgcn_global_load_lds((const uint32_t*)(gA + (size_t)(32 * i) * DIN + kt * 64),
                                             (uint32_t*)(As + i * 4096 + tid * 16), 16, 0, 0);
        }
        __syncthreads();
        #pragma unroll
        for (int kk = 0; kk < 2; ++kk) {
            short8 av[2], bv[8];
            #pragma unroll
            for (int m = 0; m < 2; ++m) {
                int row = wave * 32 + m * 16 + lr;
                int cc = (kk * 4 + lk) ^ (row & 7);
                av[m] = *(const short8*)(Xs + row * 128 + cc * 16);
            }
            #pragma unroll
            for (int n = 0; n < 8; ++n) {
                int row = n * 16 + lr;
                int cc = (kk * 4 + lk) ^ (row & 7);
                bv[n] = *(const short8*)(As + row * 128 + cc * 16);
            }
            #pragma unroll
            for (int m = 0; m < 2; ++m)
                #pragma unroll
                for (int n = 0; n < 8; ++n)
                    acc[m][n] = __builtin_amdgcn_mfma_f32_16x16x32_bf16(av[m], bv[n], acc[m][n], 0, 0, 0);
        }
        __syncthreads();
    }
    #pragma unroll
    for (int n = 0; n < 8; ++n) {
        int col = n * 16 + lr;
        #pragma unroll
        for (int m = 0; m < 2; ++m) {
            int r0 = wave * 32 + m * 16 + lk * 4;
            #pragma unroll
            for (int j = 0; j < 4; ++j)
                part[((size_t)kc << 20) + (size_t)(row0 + r0 + j) * 128 + col] = acc[m][n][j];
        }
    }
}

// ---------- reduce split-K partials, mask by adapter, scale, cvt -> xaug tail ----------
__global__ void xa_reduce(const float* __restrict__ part, const int* __restrict__ widx,
                          __hip_bfloat16* __restrict__ xaug) {
    int t = blockIdx.x * 256 + threadIdx.x;   // < 8192*128
    int s = t >> 7, c = t & 127;
    float sum = part[t] + part[(1 << 20) + t] + part[(2 << 20) + t] + part[(3 << 20) + t];
    int l = widx[s];
    float v = ((c >> 4) == l) ? 2.0f * sum : 0.0f;
    xaug[(size_t)s * KAUG + 4096 + c] = __float2bfloat16(v);
}

// ---------- 256x256 8-phase GEMM (32x32x16 MFMA): out = Xaug @ Waug^T + bias ----------
// 8 waves (2M x 4N), per-wave 128x64 = 4x2 tiles of 32x32, BK=64, LDS 128KB dbuf.
// Per phase: {ds_read frags (B first) || stage || BAR || setprio(1) 8xMFMA(counted
// lgkm waits by compiler) setprio(0) || BAR}; counted vmcnt(6) at P4/P8.
__global__ __launch_bounds__(512, 2) void gemm8(const __hip_bfloat16* __restrict__ Xa,
                                                const __hip_bfloat16* __restrict__ Wa,
                                                const float* __restrict__ bias,
                                                float* __restrict__ out) {
    // layout: buf0.A [0,32K) buf0.B [32K,64K) buf1.A [64K,96K) buf1.B [96K,128K)
    __shared__ __attribute__((aligned(16))) char lds[131072];

    const int tid = threadIdx.x;
    const int lane = tid & 63, wave = tid >> 6;
    const int wm = wave >> 2, wn = wave & 3;
    const int l31 = lane & 31, lhi = lane >> 5;

    // bijective XCD swizzle (512 blocks, 512 % 8 == 0)
    int wg = blockIdx.x;
    int swz = (wg & 7) * 64 + (wg >> 3);
    int bm = swz >> 4, bn = swz & 15;
    const int rowA0 = bm * 256, colB0 = bn * 256;

    // staging: linear LDS dest, inverse-swizzled global source (rule #21).
    // LDS[r][c16] = G[r][c16 ^ (r&7)]
    const int sr = tid >> 3;
    const int cp = (tid & 7) ^ (sr & 7);
    const __hip_bfloat16* srcA = Xa + (size_t)(rowA0 + sr) * KAUG + cp * 8;
    const __hip_bfloat16* srcB = Wa + (size_t)(colB0 + sr) * KAUG + cp * 8;

    auto STAGE = [&](int buf, int mat, int half, int kt) {
        const __hip_bfloat16* s0 = (mat ? srcB : srcA) + (size_t)(half * 128) * KAUG + kt * 64;
        char* d = lds + buf * 65536 + mat * 32768 + half * 16384 + tid * 16;
        __builtin_amdgcn_global_load_lds((const uint32_t*)s0, (uint32_t*)d, 16, 0, 0);
        __builtin_amdgcn_global_load_lds((const uint32_t*)(s0 + (size_t)64 * KAUG),
                                         (uint32_t*)(d + 8192), 16, 0, 0);
    };

    f32x16 acc[4][2] = {};          // [mtile][ntile], 32x32 each
    short8 a[2][4];                 // [m within pair][ks]
    short8 blo[4], bhi[4];          // [ks]

    // A-frag: lane holds A[row=base+ (lane&31)][k = ks*16 + (lane>>5)*8 .. +8]
    auto LDA2 = [&](short8 (&af)[2][4], int buf, int mb) {
        const char* base = lds + buf * 65536;
        #pragma unroll
        for (int m = 0; m < 2; ++m)
            #pragma unroll
            for (int ks = 0; ks < 4; ++ks) {
                int row = wm * 128 + (mb + m) * 32 + l31;
                int cc = (ks * 2 + lhi) ^ (row & 7);
                af[m][ks] = *(const short8*)(base + row * 128 + cc * 16);
            }
    };
    // B-frag: lane holds W[col=base+(lane&31)][k = ks*16 + (lane>>5)*8 .. +8]
    auto LDB1 = [&](short8 (&bf)[4], int buf, int nt) {
        const char* base = lds + buf * 65536 + 32768;
        int row = wn * 64 + nt * 32 + l31;
        #pragma unroll
        for (int ks = 0; ks < 4; ++ks) {
            int cc = (ks * 2 + lhi) ^ (row & 7);
            bf[ks] = *(const short8*)(base + row * 128 + cc * 16);
        }
    };

#define MMQ(AF, BF, MB, NTI)                                                       \
    do {                                                                           \
        __builtin_amdgcn_s_setprio(1);                                             \
        _Pragma("unroll")                                                          \
        for (int ks = 0; ks < 4; ++ks)                                             \
            _Pragma("unroll")                                                      \
            for (int m = 0; m < 2; ++m)                                            \
                acc[(MB) + m][NTI] = __builtin_amdgcn_mfma_f32_32x32x16_bf16(      \
                    AF[m][ks], BF[ks], acc[(MB) + m][NTI], 0, 0, 0);               \
        __builtin_amdgcn_s_setprio(0);                                             \
    } while (0)

#define BAR() __builtin_amdgcn_s_barrier()
#define VM6() asm volatile("s_waitcnt vmcnt(6)" ::: "memory")

    // prologue: buf0 <- t0 (8 loads); buf1.B + buf1.A.h0 <- t1 (6 loads)
    STAGE(0, 0, 0, 0); STAGE(0, 0, 1, 0);
    STAGE(0, 1, 0, 0); STAGE(0, 1, 1, 0);
    STAGE(1, 1, 0, 1); STAGE(1, 1, 1, 1);
    STAGE(1, 0, 0, 1);
    VM6();   // buf0 landed; 6 loads (buf1.B + buf1.A.h0) in flight
    BAR();

    #pragma unroll 1
    for (int i = 0; i < NT / 2; ++i) {
        int t1 = 2 * i + 1;
        int t2 = 2 * i + 2; if (t2 > NT - 1) t2 = NT - 1;   // clamp keeps vmcnt uniform
        int t3 = 2 * i + 3; if (t3 > NT - 1) t3 = NT - 1;
        // P1: buf0 tiles(0,1)xN0; stage buf1.A.h1 <- t1
        LDB1(blo, 0, 0); LDA2(a, 0, 0);
        STAGE(1, 0, 1, t1);
        BAR();
        MMQ(a, blo, 0, 0);
        BAR();
        // P2: tiles(0,1)xN1
        LDB1(bhi, 0, 1);
        BAR();
        MMQ(a, bhi, 0, 1);
        BAR();
        // P3: tiles(2,3)xN1; stage buf0.B.h0 <- t2 (buf0.B reads all drained by P2's MFMAs)
        LDA2(a, 0, 2);
        STAGE(0, 1, 0, t2);
        BAR();
        MMQ(a, bhi, 2, 1);
        BAR();
        // P4: tiles(2,3)xN0; stage buf0.B.h1 + buf0.A.h0 <- t2; vmcnt(6) -> buf1 ready
        STAGE(0, 1, 1, t2); STAGE(0, 0, 0, t2);
        VM6();
        BAR();
        MMQ(a, blo, 2, 0);
        BAR();
        // P5: buf1 tiles(0,1)xN0; stage buf0.A.h1 <- t2
        LDB1(blo, 1, 0); LDA2(a, 1, 0);
        STAGE(0, 0, 1, t2);
        BAR();
        MMQ(a, blo, 0, 0);
        BAR();
        // P6: tiles(0,1)xN1
        LDB1(bhi, 1, 1);
        BAR();
        MMQ(a, bhi, 0, 1);
        BAR();
        // P7: tiles(2,3)xN1; stage buf1.B.h0 <- t3
        LDA2(a, 1, 2);
        STAGE(1, 1, 0, t3);
        BAR();
        MMQ(a, bhi, 2, 1);
        BAR();
        // P8: tiles(2,3)xN0; stage buf1.B.h1 + buf1.A.h0 <- t3; vmcnt(6) -> buf0 ready
        STAGE(1, 1, 1, t3); STAGE(1, 0, 0, t3);
        VM6();
        BAR();
        MMQ(a, blo, 2, 0);
        BAR();
    }

    // epilogue: 32x32 C/D map col=lane&31, row=(reg&3)+8*(reg>>2)+4*(lane>>5)  [m74/m101]
    #pragma unroll
    for (int nt = 0; nt < 2; ++nt) {
        int col = colB0 + wn * 64 + nt * 32 + l31;
        float bv = bias[col];
        #pragma unroll
        for (int mt = 0; mt < 4; ++mt) {
            int rbase = rowA0 + wm * 128 + mt * 32 + 4 * lhi;
            #pragma unroll
            for (int r = 0; r < 16; ++r) {
                int row = rbase + (r & 3) + 8 * (r >> 2);
                out[(size_t)row * DOUT + col] = acc[mt][nt][r] + bv;
            }
        }
    }
#undef MMQ
#undef BAR
#undef VM6
}

extern "C" void kernel_launch(void* const* d_in, const int* in_sizes, int n_in,
                              void* d_out, int out_size, void* d_ws, size_t ws_size,
                              hipStream_t stream) {
    const float* x      = (const float*)d_in[0];
    const float* weight = (const float*)d_in[1];
    const float* bias   = (const float*)d_in[2];
    const float* A_buf  = (const float*)d_in[3];
    const float* B_buf  = (const float*)d_in[4];
    const int*   widx   = (const int*)d_in[5];
    float* out = (float*)d_out;

    __hip_bfloat16* xaug = (__hip_bfloat16*)d_ws;                                    // [8192][4224]
    __hip_bfloat16* waug = (__hip_bfloat16*)((char*)d_ws + (size_t)SDIM * KAUG * 2); // [4096][4224]
    // d_out doubles as scratch before gemm8 overwrites it:
    __hip_bfloat16* abf  = (__hip_bfloat16*)d_out;                    // [128][4096] bf16 = 1MB
    float*          part = (float*)((char*)d_out + (1 << 20));        // [4][8192][128] f32 = 16MB

    // x -> bf16 into xaug[:, 0:4096]
    {
        long total = (long)SDIM * DIN;
        cvt_f32_to_bf16_aug<<<(int)((total / 8 + 255) / 256), 256, 0, stream>>>(x, xaug, total);
    }
    // weight -> bf16 into waug[:, 0:4096]
    {
        long total = (long)DOUT * DIN;
        cvt_f32_to_bf16_aug<<<(int)((total / 8 + 255) / 256), 256, 0, stream>>>(weight, waug, total);
    }
    // B tail into waug[:, 4096:] + A -> bf16
    prep_small<<<2048 + 256, 256, 0, stream>>>(B_buf, A_buf, waug, abf);
    // XA_all partials (split-K x4)
    xa_gemm<<<64 * 4, 256, 0, stream>>>(xaug, abf, part);
    // reduce + adapter mask + scale -> xaug tail
    xa_reduce<<<(SDIM * 128) / 256, 256, 0, stream>>>(part, widx, xaug);
    // 8-phase 256^2 GEMM + bias
    gemm8<<<(SDIM / 256) * (DOUT / 256), 512, 0, stream>>>(xaug, waug, bias, out);
}

// Round 5
// 319.451 us; speedup vs baseline: 1.1067x; 1.1067x over previous
//
#include <hip/hip_runtime.h>
#include <hip/hip_bf16.h>
#include <cstdint>

#define SDIM 8192
#define DIN  4096
#define DOUT 4096
#define KAUG 4224   // 4096 + 8*16 LoRA extension
#define NADP 8
#define RLORA 16
#define NT 66       // K-tiles of 64

typedef __attribute__((ext_vector_type(8))) short short8;
typedef __attribute__((ext_vector_type(4))) float f32x4;

// ---------- conversion: f32 [rows][4096] -> bf16 [rows][KAUG] (first 4096 cols) ----------
__global__ void cvt_f32_to_bf16_aug(const float* __restrict__ src,
                                    __hip_bfloat16* __restrict__ dst,
                                    long total_elems) {
    long tid = (long)blockIdx.x * blockDim.x + threadIdx.x;
    long e = tid * 8;
    if (e >= total_elems) return;
    int s = (int)(e >> 12);
    int k = (int)(e & 4095);
    const float4* p = (const float4*)(src + e);
    float4 v0 = p[0], v1 = p[1];
    union { __hip_bfloat16 h[8]; short8 v; } u;
    u.h[0] = __float2bfloat16(v0.x); u.h[1] = __float2bfloat16(v0.y);
    u.h[2] = __float2bfloat16(v0.z); u.h[3] = __float2bfloat16(v0.w);
    u.h[4] = __float2bfloat16(v1.x); u.h[5] = __float2bfloat16(v1.y);
    u.h[6] = __float2bfloat16(v1.z); u.h[7] = __float2bfloat16(v1.w);
    *(short8*)(dst + (size_t)s * KAUG + k) = u.v;
}

// ---------- B tail into waug + A_all f32->bf16 into abf ----------
__global__ void prep_small(const float* __restrict__ B0, const float* __restrict__ A,
                           __hip_bfloat16* __restrict__ waug, __hip_bfloat16* __restrict__ abf) {
    int t = blockIdx.x * 256 + threadIdx.x;
    if (blockIdx.x < 2048) {           // btail: DOUT*128 elems
        int n = t >> 7, c = t & 127;
        int l = c >> 4, r = c & 15;
        waug[(size_t)n * KAUG + 4096 + c] =
            __float2bfloat16(B0[((size_t)l * DOUT + n) * RLORA + r]);
    } else {                           // A cvt: 128*4096 elems, 8/thread
        long e = (long)(t - 2048 * 256) * 8;
        const float4* p = (const float4*)(A + e);
        float4 v0 = p[0], v1 = p[1];
        union { __hip_bfloat16 h[8]; short8 v; } u;
        u.h[0] = __float2bfloat16(v0.x); u.h[1] = __float2bfloat16(v0.y);
        u.h[2] = __float2bfloat16(v0.z); u.h[3] = __float2bfloat16(v0.w);
        u.h[4] = __float2bfloat16(v1.x); u.h[5] = __float2bfloat16(v1.y);
        u.h[6] = __float2bfloat16(v1.z); u.h[7] = __float2bfloat16(v1.w);
        *(short8*)(abf + e) = u.v;
    }
}

// ---------- XA_all split-K mini-GEMM: part[kc][8192][128] = Xa[:, kc*1024:+1024] @ Ab^T ----------
__global__ __launch_bounds__(256) void xa_gemm(const __hip_bfloat16* __restrict__ Xa,
                                               const __hip_bfloat16* __restrict__ Ab,
                                               float* __restrict__ part) {
    __shared__ __attribute__((aligned(16))) char sm[32768];
    char* Xs = sm;              // [128][64] bf16
    char* As = sm + 16384;      // [128][64] bf16
    const int tid = threadIdx.x, lane = tid & 63, wave = tid >> 6;
    const int mt = blockIdx.x >> 2, kc = blockIdx.x & 3;
    const int row0 = mt * 128, k0 = kc * 1024;
    const int sr = tid >> 3;                 // 0..31
    const int cp = (tid & 7) ^ (sr & 7);
    const __hip_bfloat16* gX = Xa + (size_t)(row0 + sr) * KAUG + k0 + cp * 8;
    const __hip_bfloat16* gA = Ab + (size_t)sr * DIN + k0 + cp * 8;
    const int lr = lane & 15, lk = lane >> 4;
    f32x4 acc[2][8] = {};
    for (int kt = 0; kt < 16; ++kt) {
        #pragma unroll
        for (int i = 0; i < 4; ++i) {
            __builtin_amdgcn_global_load_lds((const uint32_t*)(gX + (size_t)(32 * i) * KAUG + kt * 64),
                                             (uint32_t*)(Xs + i * 4096 + tid * 16), 16, 0, 0);
            __builtin_amdgcn_global_load_lds((const uint32_t*)(gA + (size_t)(32 * i) * DIN + kt * 64),
                                             (uint32_t*)(As + i * 4096 + tid * 16), 16, 0, 0);
        }
        __syncthreads();
        #pragma unroll
        for (int kk = 0; kk < 2; ++kk) {
            short8 av[2], bv[8];
            #pragma unroll
            for (int m = 0; m < 2; ++m) {
                int row = wave * 32 + m * 16 + lr;
                int cc = (kk * 4 + lk) ^ (row & 7);
                av[m] = *(const short8*)(Xs + row * 128 + cc * 16);
            }
            #pragma unroll
            for (int n = 0; n < 8; ++n) {
                int row = n * 16 + lr;
                int cc = (kk * 4 + lk) ^ (row & 7);
                bv[n] = *(const short8*)(As + row * 128 + cc * 16);
            }
            #pragma unroll
            for (int m = 0; m < 2; ++m)
                #pragma unroll
                for (int n = 0; n < 8; ++n)
                    acc[m][n] = __builtin_amdgcn_mfma_f32_16x16x32_bf16(av[m], bv[n], acc[m][n], 0, 0, 0);
        }
        __syncthreads();
    }
    #pragma unroll
    for (int n = 0; n < 8; ++n) {
        int col = n * 16 + lr;
        #pragma unroll
        for (int m = 0; m < 2; ++m) {
            int r0 = wave * 32 + m * 16 + lk * 4;
            #pragma unroll
            for (int j = 0; j < 4; ++j)
                part[((size_t)kc << 20) + (size_t)(row0 + r0 + j) * 128 + col] = acc[m][n][j];
        }
    }
}

// ---------- reduce split-K partials, mask by adapter, scale, cvt -> xaug tail ----------
__global__ void xa_reduce(const float* __restrict__ part, const int* __restrict__ widx,
                          __hip_bfloat16* __restrict__ xaug) {
    int t = blockIdx.x * 256 + threadIdx.x;   // < 8192*128
    int s = t >> 7, c = t & 127;
    float sum = part[t] + part[(1 << 20) + t] + part[(2 << 20) + t] + part[(3 << 20) + t];
    int l = widx[s];
    float v = ((c >> 4) == l) ? 2.0f * sum : 0.0f;
    xaug[(size_t)s * KAUG + 4096 + c] = __float2bfloat16(v);
}

// ---------- 256x256 8-phase GEMM: out = Xaug @ Waug^T + bias ----------
// 8 waves (2M x 4N), per-wave 128x64, BK=64, LDS 128KB double-buffered.
// Staging at earliest WAR-legal phase; counted vmcnt(6) at P4/P8.
// MMQ: kk OUTERMOST so same-acc MFMAs are spaced by 8 independent ones.
__global__ __launch_bounds__(512, 2) void gemm8(const __hip_bfloat16* __restrict__ Xa,
                                                const __hip_bfloat16* __restrict__ Wa,
                                                const float* __restrict__ bias,
                                                float* __restrict__ out) {
    // layout: buf0.A [0,32K) buf0.B [32K,64K) buf1.A [64K,96K) buf1.B [96K,128K)
    __shared__ __attribute__((aligned(16))) char lds[131072];

    const int tid = threadIdx.x;
    const int lane = tid & 63, wave = tid >> 6;
    const int wm = wave >> 2, wn = wave & 3;
    const int lr = lane & 15, lk = lane >> 4;

    // bijective XCD swizzle (512 blocks, 512 % 8 == 0)
    int wg = blockIdx.x;
    int swz = (wg & 7) * 64 + (wg >> 3);
    int bm = swz >> 4, bn = swz & 15;
    const int rowA0 = bm * 256, colB0 = bn * 256;

    // staging: linear LDS dest, inverse-swizzled global source (rule #21).
    // LDS[r][c16] = G[r][c16 ^ (r&7)]
    const int sr = tid >> 3;
    const int cp = (tid & 7) ^ (sr & 7);
    const __hip_bfloat16* srcA = Xa + (size_t)(rowA0 + sr) * KAUG + cp * 8;
    const __hip_bfloat16* srcB = Wa + (size_t)(colB0 + sr) * KAUG + cp * 8;

    auto STAGE = [&](int buf, int mat, int half, int kt) {
        const __hip_bfloat16* s0 = (mat ? srcB : srcA) + (size_t)(half * 128) * KAUG + kt * 64;
        char* d = lds + buf * 65536 + mat * 32768 + half * 16384 + tid * 16;
        __builtin_amdgcn_global_load_lds((const uint32_t*)s0, (uint32_t*)d, 16, 0, 0);
        __builtin_amdgcn_global_load_lds((const uint32_t*)(s0 + (size_t)64 * KAUG),
                                         (uint32_t*)(d + 8192), 16, 0, 0);
    };

    f32x4 acc[8][4] = {};
    short8 a[4][2], blo[2][2], bhi[2][2];

    auto LDA4 = [&](short8 (&af)[4][2], int buf, int mbase) {
        const char* base = lds + buf * 65536;
        #pragma unroll
        for (int m = 0; m < 4; ++m)
            #pragma unroll
            for (int kk = 0; kk < 2; ++kk) {
                int row = wm * 128 + (mbase + m) * 16 + lr;
                int cc = (kk * 4 + lk) ^ (row & 7);
                af[m][kk] = *(const short8*)(base + row * 128 + cc * 16);
            }
    };
    auto LDB2 = [&](short8 (&bf)[2][2], int buf, int nbase) {
        const char* base = lds + buf * 65536 + 32768;
        #pragma unroll
        for (int n = 0; n < 2; ++n)
            #pragma unroll
            for (int kk = 0; kk < 2; ++kk) {
                int row = wn * 64 + (nbase + n) * 16 + lr;
                int cc = (kk * 4 + lk) ^ (row & 7);
                bf[n][kk] = *(const short8*)(base + row * 128 + cc * 16);
            }
    };

// kk outermost: the 8 (m,n) MFMAs within one kk are pairwise independent,
// so same-acc repeats (kk=0 -> kk=1) are separated by 8 instructions.
#define MMQ(AF, BF, MB, NB)                                                        \
    do {                                                                           \
        __builtin_amdgcn_s_setprio(1);                                             \
        _Pragma("unroll")                                                          \
        for (int kk = 0; kk < 2; ++kk)                                             \
            _Pragma("unroll")                                                      \
            for (int m = 0; m < 4; ++m)                                            \
                _Pragma("unroll")                                                  \
                for (int n = 0; n < 2; ++n)                                        \
                    acc[(MB) + m][(NB) + n] = __builtin_amdgcn_mfma_f32_16x16x32_bf16( \
                        AF[m][kk], BF[n][kk], acc[(MB) + m][(NB) + n], 0, 0, 0);   \
        __builtin_amdgcn_s_setprio(0);                                             \
    } while (0)

#define BAR() __builtin_amdgcn_s_barrier()
#define LGK0() asm volatile("s_waitcnt lgkmcnt(0)")
#define VM6() asm volatile("s_waitcnt vmcnt(6)" ::: "memory")

    // prologue: buf0 <- t0 (8 loads); buf1.B + buf1.A.h0 <- t1 (6 loads)
    STAGE(0, 0, 0, 0); STAGE(0, 0, 1, 0);
    STAGE(0, 1, 0, 0); STAGE(0, 1, 1, 0);
    STAGE(1, 1, 0, 1); STAGE(1, 1, 1, 1);
    STAGE(1, 0, 0, 1);
    VM6();   // buf0 landed; 6 loads (buf1.B + buf1.A.h0) in flight
    BAR();

    #pragma unroll 1
    for (int i = 0; i < NT / 2; ++i) {
        int t1 = 2 * i + 1;
        int t2 = 2 * i + 2; if (t2 > NT - 1) t2 = NT - 1;   // clamp keeps vmcnt uniform
        int t3 = 2 * i + 3; if (t3 > NT - 1) t3 = NT - 1;
        // P1: compute buf0 Q(0..3,0..1); stage buf1.A.h1 <- t1
        LDA4(a, 0, 0); LDB2(blo, 0, 0);
        STAGE(1, 0, 1, t1);
        BAR(); LGK0();
        MMQ(a, blo, 0, 0);
        BAR();
        // P2: Q(0..3,2..3); no stage
        LDB2(bhi, 0, 2);
        BAR(); LGK0();
        MMQ(a, bhi, 0, 2);
        BAR();
        // P3: Q(4..7,2..3); stage buf0.B.h0 <- t2 (buf0.B free after P2)
        LDA4(a, 0, 4);
        STAGE(0, 1, 0, t2);
        BAR(); LGK0();
        MMQ(a, bhi, 4, 2);
        BAR();
        // P4: Q(4..7,0..1); stage buf0.B.h1 + buf0.A.h0 <- t2; vmcnt(6) -> buf1 ready
        STAGE(0, 1, 1, t2); STAGE(0, 0, 0, t2);
        VM6();
        BAR();
        MMQ(a, blo, 4, 0);
        BAR();
        // P5: compute buf1 Q(0..3,0..1); stage buf0.A.h1 <- t2
        LDA4(a, 1, 0); LDB2(blo, 1, 0);
        STAGE(0, 0, 1, t2);
        BAR(); LGK0();
        MMQ(a, blo, 0, 0);
        BAR();
        // P6: Q(0..3,2..3); no stage
        LDB2(bhi, 1, 2);
        BAR(); LGK0();
        MMQ(a, bhi, 0, 2);
        BAR();
        // P7: Q(4..7,2..3); stage buf1.B.h0 <- t3 (buf1.B free after P6)
        LDA4(a, 1, 4);
        STAGE(1, 1, 0, t3);
        BAR(); LGK0();
        MMQ(a, bhi, 4, 2);
        BAR();
        // P8: Q(4..7,0..1); stage buf1.B.h1 + buf1.A.h0 <- t3; vmcnt(6) -> buf0 ready
        STAGE(1, 1, 1, t3); STAGE(1, 0, 0, t3);
        VM6();
        BAR();
        MMQ(a, blo, 4, 0);
        BAR();
    }

    // epilogue: C/D map col=lane&15, row=(lane>>4)*4+j  [m89]
    #pragma unroll
    for (int n = 0; n < 4; ++n) {
        int col = colB0 + wn * 64 + n * 16 + lr;
        float bv = bias[col];
        #pragma unroll
        for (int m = 0; m < 8; ++m) {
            int row0 = rowA0 + wm * 128 + m * 16 + lk * 4;
            #pragma unroll
            for (int j = 0; j < 4; ++j) {
                out[(size_t)(row0 + j) * DOUT + col] = acc[m][n][j] + bv;
            }
        }
    }
#undef MMQ
#undef BAR
#undef LGK0
#undef VM6
}

extern "C" void kernel_launch(void* const* d_in, const int* in_sizes, int n_in,
                              void* d_out, int out_size, void* d_ws, size_t ws_size,
                              hipStream_t stream) {
    const float* x      = (const float*)d_in[0];
    const float* weight = (const float*)d_in[1];
    const float* bias   = (const float*)d_in[2];
    const float* A_buf  = (const float*)d_in[3];
    const float* B_buf  = (const float*)d_in[4];
    const int*   widx   = (const int*)d_in[5];
    float* out = (float*)d_out;

    __hip_bfloat16* xaug = (__hip_bfloat16*)d_ws;                                    // [8192][4224]
    __hip_bfloat16* waug = (__hip_bfloat16*)((char*)d_ws + (size_t)SDIM * KAUG * 2); // [4096][4224]
    // d_out doubles as scratch before gemm8 overwrites it:
    __hip_bfloat16* abf  = (__hip_bfloat16*)d_out;                    // [128][4096] bf16 = 1MB
    float*          part = (float*)((char*)d_out + (1 << 20));        // [4][8192][128] f32 = 16MB

    // x -> bf16 into xaug[:, 0:4096]
    {
        long total = (long)SDIM * DIN;
        cvt_f32_to_bf16_aug<<<(int)((total / 8 + 255) / 256), 256, 0, stream>>>(x, xaug, total);
    }
    // weight -> bf16 into waug[:, 0:4096]
    {
        long total = (long)DOUT * DIN;
        cvt_f32_to_bf16_aug<<<(int)((total / 8 + 255) / 256), 256, 0, stream>>>(weight, waug, total);
    }
    // B tail into waug[:, 4096:] + A -> bf16
    prep_small<<<2048 + 256, 256, 0, stream>>>(B_buf, A_buf, waug, abf);
    // XA_all partials (split-K x4)
    xa_gemm<<<64 * 4, 256, 0, stream>>>(xaug, abf, part);
    // reduce + adapter mask + scale -> xaug tail
    xa_reduce<<<(SDIM * 128) / 256, 256, 0, stream>>>(part, widx, xaug);
    // 8-phase 256^2 GEMM + bias
    gemm8<<<(SDIM / 256) * (DOUT / 256), 512, 0, stream>>>(xaug, waug, bias, out);
}